// Round 3
// baseline (474.618 us; speedup 1.0000x reference)
//
#include <hip/hip_runtime.h>
#include <hip/hip_bf16.h>

typedef __bf16 bf16;
typedef __attribute__((ext_vector_type(8))) __bf16 bf16x8;
typedef __attribute__((ext_vector_type(4))) __bf16 bf16x4;
typedef __attribute__((ext_vector_type(4))) float f32x4;

typedef const __attribute__((address_space(1))) void* gptr_t;
typedef __attribute__((address_space(3))) void* sptr_t;

__device__ __forceinline__ void gload16(const void* g, void* l) {
  __builtin_amdgcn_global_load_lds((gptr_t)g, (sptr_t)l, 16, 0, 0);
}

#define MFMA_BF16(a, b, c) __builtin_amdgcn_mfma_f32_16x16x32_bf16((a), (b), (c), 0, 0, 0)

// raw barrier with compile-time memory fences (prevents LDS access reordering
// across it; does NOT emit the vmcnt(0) drain that __syncthreads carries)
#define BAR() do { asm volatile("" ::: "memory"); __builtin_amdgcn_s_barrier(); asm volatile("" ::: "memory"); } while (0)

namespace {
constexpr int kB = 2, kS = 2048, kE = 2048, kN = 16, kH = 128;
constexpr float kScale = 0.08838834764831845f;  // 1/sqrt(128)
constexpr float kLog2e = 1.4426950408889634f;
}

// ---------------- f32 -> bf16 convert (vectorized) ----------------
__global__ void k_cvt(const float* __restrict__ in, bf16* __restrict__ out) {
  int i = blockIdx.x * 256 + threadIdx.x;
  float4 v = reinterpret_cast<const float4*>(in)[i];
  bf16x4 o = { (bf16)v.x, (bf16)v.y, (bf16)v.z, (bf16)v.w };
  reinterpret_cast<bf16x4*>(out)[i] = o;
}

// ------------- transpose-convert: in[2048][2048] f32 -> out[c][r] bf16 -------------
__global__ void k_tconv(const float* __restrict__ in, bf16* __restrict__ out) {
  __shared__ bf16 tile[64][66];
  int bx = blockIdx.x & 31, by = blockIdx.x >> 5;
  int r0 = by * 64, c0 = bx * 64;
  int t = threadIdx.x;
  int c = t & 63, rb = t >> 6;
#pragma unroll
  for (int j = 0; j < 16; ++j) {
    int r = rb + j * 4;
    tile[r][c] = (bf16)in[(size_t)(r0 + r) * 2048 + c0 + c];
  }
  __syncthreads();
  int rr = t & 63;
#pragma unroll
  for (int j = 0; j < 16; ++j) {
    int cc = rb + j * 4;
    out[(size_t)(c0 + cc) * 2048 + r0 + rr] = tile[rr][cc];
  }
}

// ------------- V transpose: V[bn][S][H] -> Vt[bn][H][S] (bf16) -------------
__global__ void k_vtrans(const bf16* __restrict__ V, bf16* __restrict__ Vt) {
  __shared__ bf16 tile[64][66];
  int bid = blockIdx.x;
  int bn = bid >> 6;
  int s0 = ((bid >> 1) & 31) * 64;
  int h0 = (bid & 1) * 64;
  size_t base = (size_t)bn * kS * kH;
  int t = threadIdx.x, c = t & 63, rb = t >> 6;
#pragma unroll
  for (int j = 0; j < 16; ++j) {
    int r = rb + j * 4;
    tile[r][c] = V[base + (size_t)(s0 + r) * kH + h0 + c];
  }
  __syncthreads();
#pragma unroll
  for (int j = 0; j < 16; ++j) {
    int hh = rb + j * 4;
    Vt[base + (size_t)(h0 + hh) * kS + s0 + (t & 63)] = tile[t & 63][hh];
  }
}

// ------------- RoPE in-place on Q and K, layout [B,N,S,H] -------------
__global__ void k_rope(bf16* __restrict__ Qd, bf16* __restrict__ Kd) {
  int tid = blockIdx.x * 256 + threadIdx.x;   // B*N*S*64 total
  int i = tid & 63;
  int s = (tid >> 6) & (kS - 1);
  int bn = tid >> 17;
  size_t base = ((size_t)bn * kS + s) * kH;
  float inv = exp2f(-(float)i * 0.20762050593046457f);  // 10000^(-i/64)
  float ang = (float)s * inv;
  float sn, cs;
  sincosf(ang, &sn, &cs);
  float q1 = (float)Qd[base + i], q2 = (float)Qd[base + i + 64];
  Qd[base + i]      = (bf16)(q1 * cs - q2 * sn);
  Qd[base + i + 64] = (bf16)(q2 * cs + q1 * sn);
  float k1 = (float)Kd[base + i], k2 = (float)Kd[base + i + 64];
  Kd[base + i]      = (bf16)(k1 * cs - k2 * sn);
  Kd[base + i + 64] = (bf16)(k2 * cs + k1 * sn);
}

// ======== 256x256 8-phase GEMM (T2+T3+T4+T5), BK=64, 8 waves (2M x 4N) ========
// A [M][2048] bf16 row-major, Bt [Ncols][2048] bf16 (weights pre-transposed).
// MODE 0: QKV fused, Ncols=6144, scatter bf16 to [B,N,S,H] x {Q,K,V}.
// MODE 1: Ncols=2048, write f32 [M][2048].
// LDS: per operand [2 buf][2 half][128 rows][64 k] bf16, st_16x32 swizzle:
// phys = logical ^ (((logical>>9)&1)<<5); gload_lds dest is linear, so the
// inverse swizzle is applied to the per-lane GLOBAL source address (rule #21).

__device__ __forceinline__ void stage_half(const bf16* __restrict__ src, size_t row0,
                                           int k0, char* slot, int t) {
#pragma unroll
  for (int i = 0; i < 2; ++i) {
    int idx = i * 512 + t;          // 0..1023
    int d = idx * 16;               // physical LDS byte this thread fills
    int lb = d ^ (((d >> 9) & 1) << 5);  // logical byte (involution)
    int r = lb >> 7;                // logical row 0..127
    int kc = (lb & 127) >> 1;       // logical k-col (bf16 elems), mult of 8
    gload16(src + (row0 + r) * 2048 + k0 + kc,
            slot + i * 8192 + (t >> 6) * 1024);
  }
}

template <int MODE>
__global__ __launch_bounds__(512, 2) void k_gemm8(const bf16* __restrict__ Aq,
                                                  const bf16* __restrict__ Akv,
                                                  const bf16* __restrict__ Bt,
                                                  void* __restrict__ Cout) {
  constexpr int NTN = (MODE == 0) ? 24 : 8;   // N-tiles
  constexpr int NT = 32;                      // K-tiles (2048/64)
  __shared__ __align__(16) char AsB[2][2][16384];
  __shared__ __align__(16) char BsB[2][2][16384];
  int bid = blockIdx.x;
  constexpr int nblk = 16 * NTN;
  int swz = (bid & 7) * (nblk >> 3) + (bid >> 3);  // XCD-aware (nblk%8==0)
  int mt = swz / NTN, nt = swz - mt * NTN;
  size_t m0 = (size_t)mt * 256;
  int n0 = nt * 256;
  const bf16* A = (MODE == 0 && nt >= 8) ? Akv : Aq;  // K,V read x_kv
  int t = threadIdx.x, wid = t >> 6, lane = t & 63;
  int l16 = lane & 15, lq = lane >> 4;
  int wr = wid >> 2, wc = wid & 3;          // 2M x 4N wave grid
  int bhalf = wc >> 1;                      // B half this wave reads
  int brow0 = ((wc & 1) << 6) + l16;        // row-in-half base for B frags

  f32x4 acc[8][4] = {};
  bf16x8 af[4], bf[4];

  // ---- prologue: B(0), A(0), B(1); allow B(1) (4 loads) in flight ----
  stage_half(Bt, (size_t)n0,       0, BsB[0][0], t);
  stage_half(Bt, (size_t)n0 + 128, 0, BsB[0][1], t);
  stage_half(A,  m0,               0, AsB[0][0], t);
  stage_half(A,  m0 + 128,         0, AsB[0][1], t);
  stage_half(Bt, (size_t)n0,      64, BsB[1][0], t);
  stage_half(Bt, (size_t)n0 + 128, 64, BsB[1][1], t);
  asm volatile("s_waitcnt vmcnt(4)" ::: "memory");
  BAR();

  for (int kt = 0; kt < NT; ++kt) {
    int buf = kt & 1, nbuf = buf ^ 1;
    // ---------- P1: mg=0, kf=0 (reads B kf0 too); stage A0(kt+1) ----------
#pragma unroll
    for (int j = 0; j < 4; ++j) {
      int l = ((j * 16 + l16) << 7) + (lq << 4);
      af[j] = *(const bf16x8*)(AsB[buf][wr] + (l ^ (((l >> 9) & 1) << 5)));
    }
#pragma unroll
    for (int nf = 0; nf < 4; ++nf) {
      int l = ((brow0 + nf * 16) << 7) + (lq << 4);
      bf[nf] = *(const bf16x8*)(BsB[buf][bhalf] + (l ^ (((l >> 9) & 1) << 5)));
    }
    if (kt + 1 < NT) stage_half(A, m0, (kt + 1) * 64, AsB[nbuf][0], t);
    BAR();
    __builtin_amdgcn_s_setprio(1);
#pragma unroll
    for (int j = 0; j < 4; ++j)
#pragma unroll
      for (int nf = 0; nf < 4; ++nf)
        acc[j][nf] = MFMA_BF16(af[j], bf[nf], acc[j][nf]);
    __builtin_amdgcn_s_setprio(0);
    BAR();
    // ---------- P2: mg=1, kf=0; stage A1(kt+1) ----------
#pragma unroll
    for (int j = 0; j < 4; ++j) {
      int l = (((j + 4) * 16 + l16) << 7) + (lq << 4);
      af[j] = *(const bf16x8*)(AsB[buf][wr] + (l ^ (((l >> 9) & 1) << 5)));
    }
    if (kt + 1 < NT) stage_half(A, m0 + 128, (kt + 1) * 64, AsB[nbuf][1], t);
    BAR();
    __builtin_amdgcn_s_setprio(1);
#pragma unroll
    for (int j = 0; j < 4; ++j)
#pragma unroll
      for (int nf = 0; nf < 4; ++nf)
        acc[j + 4][nf] = MFMA_BF16(af[j], bf[nf], acc[j + 4][nf]);
    __builtin_amdgcn_s_setprio(0);
    BAR();
    // ---------- P3: mg=0, kf=1 (reads B kf1) ----------
#pragma unroll
    for (int j = 0; j < 4; ++j) {
      int l = ((j * 16 + l16) << 7) + 64 + (lq << 4);
      af[j] = *(const bf16x8*)(AsB[buf][wr] + (l ^ (((l >> 9) & 1) << 5)));
    }
#pragma unroll
    for (int nf = 0; nf < 4; ++nf) {
      int l = ((brow0 + nf * 16) << 7) + 64 + (lq << 4);
      bf[nf] = *(const bf16x8*)(BsB[buf][bhalf] + (l ^ (((l >> 9) & 1) << 5)));
    }
    BAR();
    __builtin_amdgcn_s_setprio(1);
#pragma unroll
    for (int j = 0; j < 4; ++j)
#pragma unroll
      for (int nf = 0; nf < 4; ++nf)
        acc[j][nf] = MFMA_BF16(af[j], bf[nf], acc[j][nf]);
    __builtin_amdgcn_s_setprio(0);
    BAR();
    // ---------- P4: mg=1, kf=1; stage B0,B1(kt+2); counted vmcnt ----------
#pragma unroll
    for (int j = 0; j < 4; ++j) {
      int l = (((j + 4) * 16 + l16) << 7) + 64 + (lq << 4);
      af[j] = *(const bf16x8*)(AsB[buf][wr] + (l ^ (((l >> 9) & 1) << 5)));
    }
    if (kt + 2 < NT) {
      stage_half(Bt, (size_t)n0,       (kt + 2) * 64, BsB[buf][0], t);
      stage_half(Bt, (size_t)n0 + 128, (kt + 2) * 64, BsB[buf][1], t);
    }
    BAR();
    __builtin_amdgcn_s_setprio(1);
#pragma unroll
    for (int j = 0; j < 4; ++j)
#pragma unroll
      for (int nf = 0; nf < 4; ++nf)
        acc[j + 4][nf] = MFMA_BF16(af[j], bf[nf], acc[j + 4][nf]);
    __builtin_amdgcn_s_setprio(0);
    if (kt < NT - 2)       asm volatile("s_waitcnt vmcnt(4)" ::: "memory");
    else if (kt == NT - 2) asm volatile("s_waitcnt vmcnt(0)" ::: "memory");
    BAR();
  }

  // ---- epilogue: C write ----
#pragma unroll
  for (int mf = 0; mf < 8; ++mf) {
    int rowb = (int)m0 + wr * 128 + mf * 16 + lq * 4;
#pragma unroll
    for (int nf = 0; nf < 4; ++nf) {
      int col = n0 + wc * 64 + nf * 16 + l16;
#pragma unroll
      for (int r = 0; r < 4; ++r) {
        float v = acc[mf][nf][r];
        int mrow = rowb + r;
        if (MODE == 0) {
          int grp = col >> 11, cw = col & 2047;
          int b = mrow >> 11, s = mrow & 2047, n = cw >> 7, h = cw & 127;
          ((bf16*)Cout)[(size_t)grp * 8388608 +
                        (((size_t)(b * 16 + n) * 2048 + s) << 7) + h] = (bf16)v;
        } else {
          ((float*)Cout)[((size_t)mrow << 11) + col] = v;
        }
      }
    }
  }
}

// ------------- Flash attention (causal): Q,K [B,N,S,H], Vt [B,N,H,S] -> AO [B,S,N,H] -------------
__global__ __launch_bounds__(512, 4) void k_attn(const bf16* __restrict__ Q,
                                                 const bf16* __restrict__ Kg,
                                                 const bf16* __restrict__ Vt,
                                                 bf16* __restrict__ AO) {
  __shared__ __align__(16) bf16 Ks[64 * 128];   // [s'][h], chunk-swizzled
  __shared__ __align__(16) bf16 Vs[128 * 64];   // [h][s'], chunk-swizzled
  __shared__ __align__(16) bf16 Ps[8][16][72];  // per-wave P, padded
  int bid = blockIdx.x;
  int half = bid >> 8;
  int bn = (half << 4) | ((bid >> 4) & 15);
  int qt = (bid & 15) ^ (half ? 15 : 0);
  int q0 = qt * 128;
  int t = threadIdx.x, wid = t >> 6, lane = t & 63;
  int l16 = lane & 15, lq = lane >> 4;
  size_t bnSH = (size_t)bn * kS * kH;

  int qrow_a = q0 + wid * 16 + l16;
  bf16x8 qf[4];
#pragma unroll
  for (int ks = 0; ks < 4; ++ks)
    qf[ks] = *(const bf16x8*)(Q + bnSH + (size_t)qrow_a * kH + ks * 32 + lq * 8);

  f32x4 oacc[8] = {};
  float mrun[4], lrun[4];
#pragma unroll
  for (int r = 0; r < 4; ++r) { mrun[r] = -1e30f; lrun[r] = 0.f; }

  int ntiles = (q0 + 128) >> 6;
  for (int kt = 0; kt < ntiles; ++kt) {
    int kv0 = kt * 64;
#pragma unroll
    for (int i = 0; i < 2; ++i) {
      int idx = i * 512 + t;
      {
        int row = idx >> 4, ch = idx & 15;
        int gch = ch ^ (row & 7);
        gload16(Kg + bnSH + (size_t)(kv0 + row) * kH + gch * 8,
                (char*)Ks + i * 8192 + wid * 1024);
      }
      {
        int row = idx >> 3, ch = idx & 7;
        int gch = ch ^ (row & 7);
        gload16(Vt + bnSH + (size_t)row * kS + kv0 + gch * 8,
                (char*)Vs + i * 8192 + wid * 1024);
      }
    }
    __syncthreads();

    f32x4 sacc[4] = {};
#pragma unroll
    for (int ks = 0; ks < 4; ++ks) {
#pragma unroll
      for (int ni = 0; ni < 4; ++ni) {
        int sp = ni * 16 + l16;
        int hb = (ks * 32 + lq * 8) * 2;
        bf16x8 kb = *(const bf16x8*)((const char*)Ks + sp * 256 + (hb ^ ((sp & 7) << 4)));
        sacc[ni] = MFMA_BF16(qf[ks], kb, sacc[ni]);
      }
    }

    bool need_mask = (kv0 + 63) > (q0 + wid * 16);
#pragma unroll
    for (int ni = 0; ni < 4; ++ni) {
      f32x4 v = sacc[ni] * kScale;
      if (need_mask) {
#pragma unroll
        for (int r = 0; r < 4; ++r) {
          int qrow = q0 + wid * 16 + lq * 4 + r;
          int col = kv0 + ni * 16 + l16;
          if (col > qrow) v[r] = -1e30f;
        }
      }
      sacc[ni] = v;
    }

#pragma unroll
    for (int r = 0; r < 4; ++r) {
      float pm = fmaxf(fmaxf(sacc[0][r], sacc[1][r]),
                       fmaxf(sacc[2][r], sacc[3][r]));
      pm = fmaxf(pm, __shfl_xor(pm, 1));
      pm = fmaxf(pm, __shfl_xor(pm, 2));
      pm = fmaxf(pm, __shfl_xor(pm, 4));
      pm = fmaxf(pm, __shfl_xor(pm, 8));
      float mold = mrun[r];
      float mnew = fmaxf(mold, pm);
      float alpha = exp2f((mold - mnew) * kLog2e);
      mrun[r] = mnew;
      float rs = 0.f;
#pragma unroll
      for (int ni = 0; ni < 4; ++ni) {
        float p = exp2f((sacc[ni][r] - mnew) * kLog2e);
        sacc[ni][r] = p;
        rs += p;
      }
      rs += __shfl_xor(rs, 1);
      rs += __shfl_xor(rs, 2);
      rs += __shfl_xor(rs, 4);
      rs += __shfl_xor(rs, 8);
      lrun[r] = lrun[r] * alpha + rs;
#pragma unroll
      for (int nj = 0; nj < 8; ++nj) oacc[nj][r] *= alpha;
    }

#pragma unroll
    for (int ni = 0; ni < 4; ++ni)
#pragma unroll
      for (int r = 0; r < 4; ++r)
        Ps[wid][lq * 4 + r][ni * 16 + l16] = (bf16)sacc[ni][r];

#pragma unroll
    for (int ks = 0; ks < 2; ++ks) {
      bf16x8 pa = *(const bf16x8*)&Ps[wid][l16][ks * 32 + lq * 8];
#pragma unroll
      for (int nj = 0; nj < 8; ++nj) {
        int h = nj * 16 + l16;
        int sb = (ks * 64 + lq * 16) ^ ((h & 7) << 4);
        bf16x8 vb = *(const bf16x8*)((const char*)Vs + h * 128 + sb);
        oacc[nj] = MFMA_BF16(pa, vb, oacc[nj]);
      }
    }
    __syncthreads();
  }

  int b = bn >> 4, n = bn & 15;
#pragma unroll
  for (int r = 0; r < 4; ++r) {
    float inv = 1.0f / lrun[r];
    int qrow = q0 + wid * 16 + lq * 4 + r;
#pragma unroll
    for (int nj = 0; nj < 8; ++nj) {
      float v = oacc[nj][r] * inv;
      AO[(((size_t)b * kS + qrow) * kN + n) * kH + nj * 16 + l16] = (bf16)v;
    }
  }
}

extern "C" void kernel_launch(void* const* d_in, const int* in_sizes, int n_in,
                              void* d_out, int out_size, void* d_ws, size_t ws_size,
                              hipStream_t stream) {
  (void)in_sizes; (void)n_in; (void)out_size; (void)ws_size;
  const float* x_q  = (const float*)d_in[0];
  const float* x_kv = (const float*)d_in[1];
  const float* WQ   = (const float*)d_in[2];
  const float* WK   = (const float*)d_in[3];
  const float* WV   = (const float*)d_in[4];
  const float* WO   = (const float*)d_in[5];
  float* out = (float*)d_out;
  char* w = (char*)d_ws;
  const size_t MB = 1ull << 20;
  bf16* xq  = (bf16*)(w + 0 * MB);    // 16MB, reused as AO after attention input consumed
  bf16* xkv = (bf16*)(w + 16 * MB);   // 16MB, reused as Vt
  bf16* WqT = (bf16*)(w + 32 * MB);   // 8MB  -- WqT/WkT/WvT contiguous = fused [6144][2048]
  bf16* WkT = (bf16*)(w + 40 * MB);   // 8MB
  bf16* WvT = (bf16*)(w + 48 * MB);   // 8MB
  bf16* WoT = (bf16*)(w + 56 * MB);   // 8MB
  bf16* Qb  = (bf16*)(w + 64 * MB);   // 16MB [B,N,S,H]; Kb=+16MB, Vb=+32MB (grp indexed)
  bf16* Kb  = (bf16*)(w + 80 * MB);
  bf16* Vb  = (bf16*)(w + 96 * MB);
  bf16* AO  = xq;                     // [B,S,N,H]
  bf16* Vtb = xkv;                    // [B,N,H,S]

  k_cvt<<<8192, 256, 0, stream>>>(x_q, xq);
  k_cvt<<<8192, 256, 0, stream>>>(x_kv, xkv);
  k_tconv<<<1024, 256, 0, stream>>>(WQ, WqT);
  k_tconv<<<1024, 256, 0, stream>>>(WK, WkT);
  k_tconv<<<1024, 256, 0, stream>>>(WV, WvT);
  k_tconv<<<1024, 256, 0, stream>>>(WO, WoT);
  k_gemm8<0><<<384, 512, 0, stream>>>(xq, xkv, WqT, Qb);   // fused QKV
  k_rope<<<16384, 256, 0, stream>>>(Qb, Kb);
  k_vtrans<<<2048, 256, 0, stream>>>(Vb, Vtb);
  k_attn<<<512, 512, 0, stream>>>(Qb, Kb, Vtb, AO);
  k_gemm8<1><<<128, 512, 0, stream>>>(AO, AO, WoT, out);   // output proj
}

// Round 5
// 447.561 us; speedup vs baseline: 1.0605x; 1.0605x over previous
//
#include <hip/hip_runtime.h>
#include <hip/hip_bf16.h>

typedef __bf16 bf16;
typedef __attribute__((ext_vector_type(8))) __bf16 bf16x8;
typedef __attribute__((ext_vector_type(4))) __bf16 bf16x4;
typedef __attribute__((ext_vector_type(4))) float f32x4;

typedef const __attribute__((address_space(1))) void* gptr_t;
typedef __attribute__((address_space(3))) void* sptr_t;

__device__ __forceinline__ void gload16(const void* g, void* l) {
  __builtin_amdgcn_global_load_lds((gptr_t)g, (sptr_t)l, 16, 0, 0);
}

#define MFMA_BF16(a, b, c) __builtin_amdgcn_mfma_f32_16x16x32_bf16((a), (b), (c), 0, 0, 0)

// raw barrier (no vmcnt(0) drain)
#define BAR() do { asm volatile("" ::: "memory"); __builtin_amdgcn_s_barrier(); asm volatile("" ::: "memory"); } while (0)

// st-swizzle: XOR the 16B-slot index (bits 6:4) with the low 3 row bits
// (bits 9:7 of the byte offset, rows are 128B). Involution; bits>=7 unchanged.
__device__ __forceinline__ int swzb(int l) { return l ^ (((l >> 7) & 7) << 4); }

namespace {
constexpr int kB = 2, kS = 2048, kE = 2048, kN = 16, kH = 128;
constexpr float kScale = 0.08838834764831845f;  // 1/sqrt(128)
constexpr float kLog2e = 1.4426950408889634f;
}

// ---------------- f32 -> bf16 convert (vectorized) ----------------
__global__ void k_cvt(const float* __restrict__ in, bf16* __restrict__ out) {
  int i = blockIdx.x * 256 + threadIdx.x;
  float4 v = reinterpret_cast<const float4*>(in)[i];
  bf16x4 o = { (bf16)v.x, (bf16)v.y, (bf16)v.z, (bf16)v.w };
  reinterpret_cast<bf16x4*>(out)[i] = o;
}

// ------------- transpose-convert: in[2048][2048] f32 -> out[c][r] bf16 -------------
__global__ void k_tconv(const float* __restrict__ in, bf16* __restrict__ out) {
  __shared__ bf16 tile[64][66];
  int bx = blockIdx.x & 31, by = blockIdx.x >> 5;
  int r0 = by * 64, c0 = bx * 64;
  int t = threadIdx.x;
  int c = t & 63, rb = t >> 6;
#pragma unroll
  for (int j = 0; j < 16; ++j) {
    int r = rb + j * 4;
    tile[r][c] = (bf16)in[(size_t)(r0 + r) * 2048 + c0 + c];
  }
  __syncthreads();
  int rr = t & 63;
#pragma unroll
  for (int j = 0; j < 16; ++j) {
    int cc = rb + j * 4;
    out[(size_t)(c0 + cc) * 2048 + r0 + rr] = tile[rr][cc];
  }
}

// ------------- V transpose: V[bn][S][H] -> Vt[bn][H][S] (bf16) -------------
__global__ void k_vtrans(const bf16* __restrict__ V, bf16* __restrict__ Vt) {
  __shared__ bf16 tile[64][66];
  int bid = blockIdx.x;
  int bn = bid >> 6;
  int s0 = ((bid >> 1) & 31) * 64;
  int h0 = (bid & 1) * 64;
  size_t base = (size_t)bn * kS * kH;
  int t = threadIdx.x, c = t & 63, rb = t >> 6;
#pragma unroll
  for (int j = 0; j < 16; ++j) {
    int r = rb + j * 4;
    tile[r][c] = V[base + (size_t)(s0 + r) * kH + h0 + c];
  }
  __syncthreads();
#pragma unroll
  for (int j = 0; j < 16; ++j) {
    int hh = rb + j * 4;
    Vt[base + (size_t)(h0 + hh) * kS + s0 + (t & 63)] = tile[t & 63][hh];
  }
}

// ------------- trig table: ctab/stab[2048][64] -------------
__global__ void k_trig(float* __restrict__ ctab, float* __restrict__ stab) {
  int tid = blockIdx.x * 256 + threadIdx.x;   // 131072
  int s = tid >> 6, i = tid & 63;
  float inv = exp2f(-(float)i * 0.20762050593046457f);  // 10000^(-i/64)
  float ang = (float)s * inv;
  float sn, cs;
  sincosf(ang, &sn, &cs);
  ctab[tid] = cs;
  stab[tid] = sn;
}

// ------------- RoPE in-place on Q and K, layout [B,N,S,H], table-driven -------------
__global__ void k_rope(bf16* __restrict__ Qd, bf16* __restrict__ Kd,
                       const float* __restrict__ ctab, const float* __restrict__ stab) {
  int tid = blockIdx.x * 256 + threadIdx.x;   // B*N*S*64 total
  int i = tid & 63;
  int s = (tid >> 6) & (kS - 1);
  int bn = tid >> 17;
  size_t base = ((size_t)bn * kS + s) * kH;
  float cs = ctab[(s << 6) + i], sn = stab[(s << 6) + i];
  float q1 = (float)Qd[base + i], q2 = (float)Qd[base + i + 64];
  Qd[base + i]      = (bf16)(q1 * cs - q2 * sn);
  Qd[base + i + 64] = (bf16)(q2 * cs + q1 * sn);
  float k1 = (float)Kd[base + i], k2 = (float)Kd[base + i + 64];
  Kd[base + i]      = (bf16)(k1 * cs - k2 * sn);
  Kd[base + i + 64] = (bf16)(k2 * cs + k1 * sn);
}

// ======== 8-phase GEMM (T2+T3+T4+T5), BK=64, 8 waves ========
// MODE 0: 256x256 tiles, QKV fused (Ncols=6144), scatter bf16 to [B,N,S,H] x {Q,K,V}.
// MODE 1: 128x256 tiles (256 blocks, no tail), write f32 [M][2048].

__device__ __forceinline__ void stage_half(const bf16* __restrict__ src, size_t row0,
                                           int k0, char* slot, int t) {
#pragma unroll
  for (int i = 0; i < 2; ++i) {
    int idx = i * 512 + t;               // 0..1023
    int d = idx * 16;                    // physical LDS byte this thread fills
    int lb = d ^ (((d >> 7) & 7) << 4);  // logical byte (involution)
    int r = lb >> 7;                     // logical row 0..127
    int kc = (lb & 127) >> 1;            // logical k-col (bf16), 16B-aligned
    gload16(src + (row0 + r) * 2048 + k0 + kc,
            slot + i * 8192 + (t >> 6) * 1024);
  }
}

// LDS slot addressing (inline arithmetic; no static pointer arrays — hipcc
// can't emit static initializers of addrspace(3) casts)
#define ASB(b, h) ((char*)LDS + (b) * 32768 + (h) * 16384)
#define BSB(b, h) ((char*)LDS + 65536 + (b) * 32768 + (h) * 16384)
#define AS1(b)    ((char*)LDS + (b) * 16384)
#define BS1(q, h) ((char*)LDS + 32768 + (q) * 32768 + (h) * 16384)

template <int MODE>
__global__ __launch_bounds__(512, 2) void k_gemm8(const bf16* __restrict__ Aq,
                                                  const bf16* __restrict__ Akv,
                                                  const bf16* __restrict__ Bt,
                                                  void* __restrict__ Cout) {
  constexpr int NTN = (MODE == 0) ? 24 : 8;     // N-tiles
  constexpr int NTM = (MODE == 0) ? 16 : 32;    // M-tiles
  constexpr int NT = 32;                        // K-tiles (2048/64)
  constexpr int BM = (MODE == 0) ? 256 : 128;
  __shared__ __align__(16) char LDS[131072];
  int bid = blockIdx.x;
  constexpr int nblk = NTM * NTN;
  int swz = (bid & 7) * (nblk >> 3) + (bid >> 3);  // XCD-aware (nblk%8==0)
  int mt = swz / NTN, nt = swz - mt * NTN;
  size_t m0 = (size_t)mt * BM;
  int n0 = nt * 256;
  const bf16* A = (MODE == 0 && nt >= 8) ? Akv : Aq;  // K,V read x_kv
  int t = threadIdx.x, wid = t >> 6, lane = t & 63;
  int l16 = lane & 15, lq = lane >> 4;
  int wr = wid >> 2, wc = wid & 3;          // 2M x 4N wave grid
  int bhalf = wc >> 1;                      // B half this wave reads
  int brow0 = ((wc & 1) << 6) + l16;        // row-in-half base for B frags

  constexpr int MF = (MODE == 0) ? 8 : 4;
  f32x4 acc[MF][4] = {};
  bf16x8 af[4], bfr[4];

  if constexpr (MODE == 0) {
    stage_half(Bt, (size_t)n0,       0, BSB(0, 0), t);
    stage_half(Bt, (size_t)n0 + 128, 0, BSB(0, 1), t);
    stage_half(A,  m0,               0, ASB(0, 0), t);
    stage_half(A,  m0 + 128,         0, ASB(0, 1), t);
    stage_half(Bt, (size_t)n0,      64, BSB(1, 0), t);
    stage_half(Bt, (size_t)n0 + 128, 64, BSB(1, 1), t);
    asm volatile("s_waitcnt vmcnt(4)" ::: "memory");
    BAR();

    for (int kt = 0; kt < NT; ++kt) {
      int buf = kt & 1, nbuf = buf ^ 1;
      // ---------- P1: mg=0, kf=0; stage A0(kt+1) ----------
#pragma unroll
      for (int j = 0; j < 4; ++j) {
        int l = ((j * 16 + l16) << 7) + (lq << 4);
        af[j] = *(const bf16x8*)(ASB(buf, wr) + swzb(l));
      }
#pragma unroll
      for (int nf = 0; nf < 4; ++nf) {
        int l = ((brow0 + nf * 16) << 7) + (lq << 4);
        bfr[nf] = *(const bf16x8*)(BSB(buf, bhalf) + swzb(l));
      }
      if (kt + 1 < NT) stage_half(A, m0, (kt + 1) * 64, ASB(nbuf, 0), t);
      BAR();
      __builtin_amdgcn_s_setprio(1);
#pragma unroll
      for (int j = 0; j < 4; ++j)
#pragma unroll
        for (int nf = 0; nf < 4; ++nf)
          acc[j][nf] = MFMA_BF16(af[j], bfr[nf], acc[j][nf]);
      __builtin_amdgcn_s_setprio(0);
      BAR();
      // ---------- P2: mg=1, kf=0; stage A1(kt+1) ----------
#pragma unroll
      for (int j = 0; j < 4; ++j) {
        int l = (((j + 4) * 16 + l16) << 7) + (lq << 4);
        af[j] = *(const bf16x8*)(ASB(buf, wr) + swzb(l));
      }
      if (kt + 1 < NT) stage_half(A, m0 + 128, (kt + 1) * 64, ASB(nbuf, 1), t);
      BAR();
      __builtin_amdgcn_s_setprio(1);
#pragma unroll
      for (int j = 0; j < 4; ++j)
#pragma unroll
        for (int nf = 0; nf < 4; ++nf)
          acc[j + 4][nf] = MFMA_BF16(af[j], bfr[nf], acc[j + 4][nf]);
      __builtin_amdgcn_s_setprio(0);
      BAR();
      // ---------- P3: mg=0, kf=1 ----------
#pragma unroll
      for (int j = 0; j < 4; ++j) {
        int l = ((j * 16 + l16) << 7) + 64 + (lq << 4);
        af[j] = *(const bf16x8*)(ASB(buf, wr) + swzb(l));
      }
#pragma unroll
      for (int nf = 0; nf < 4; ++nf) {
        int l = ((brow0 + nf * 16) << 7) + 64 + (lq << 4);
        bfr[nf] = *(const bf16x8*)(BSB(buf, bhalf) + swzb(l));
      }
      BAR();
      __builtin_amdgcn_s_setprio(1);
#pragma unroll
      for (int j = 0; j < 4; ++j)
#pragma unroll
        for (int nf = 0; nf < 4; ++nf)
          acc[j][nf] = MFMA_BF16(af[j], bfr[nf], acc[j][nf]);
      __builtin_amdgcn_s_setprio(0);
      BAR();
      // ---------- P4: mg=1, kf=1; stage B0,B1(kt+2); counted vmcnt ----------
#pragma unroll
      for (int j = 0; j < 4; ++j) {
        int l = (((j + 4) * 16 + l16) << 7) + 64 + (lq << 4);
        af[j] = *(const bf16x8*)(ASB(buf, wr) + swzb(l));
      }
      if (kt + 2 < NT) {
        stage_half(Bt, (size_t)n0,       (kt + 2) * 64, BSB(buf, 0), t);
        stage_half(Bt, (size_t)n0 + 128, (kt + 2) * 64, BSB(buf, 1), t);
      }
      BAR();
      __builtin_amdgcn_s_setprio(1);
#pragma unroll
      for (int j = 0; j < 4; ++j)
#pragma unroll
        for (int nf = 0; nf < 4; ++nf)
          acc[j + 4][nf] = MFMA_BF16(af[j], bfr[nf], acc[j + 4][nf]);
      __builtin_amdgcn_s_setprio(0);
      if (kt < NT - 2)       asm volatile("s_waitcnt vmcnt(4)" ::: "memory");
      else if (kt == NT - 2) asm volatile("s_waitcnt vmcnt(0)" ::: "memory");
      BAR();
    }
  } else {
    // MODE 1: A double-buf at 0, B triple-buf at 32768
    stage_half(Bt, (size_t)n0,       0, BS1(0, 0), t);
    stage_half(Bt, (size_t)n0 + 128, 0, BS1(0, 1), t);
    stage_half(A,  m0,               0, AS1(0), t);
    stage_half(Bt, (size_t)n0,      64, BS1(1, 0), t);
    stage_half(Bt, (size_t)n0 + 128, 64, BS1(1, 1), t);
    asm volatile("s_waitcnt vmcnt(4)" ::: "memory");
    BAR();

    int bql = 0;  // kt % 3
    for (int kt = 0; kt < NT; ++kt) {
      char* Ab = AS1(kt & 1);
      char* Anb = AS1((kt & 1) ^ 1);
      char* Bb = BS1(bql, bhalf);
      int bq2 = bql + 2; if (bq2 >= 3) bq2 -= 3;
      // ---------- P1: kf=0, nf{0,1}; stage A(kt+1) ----------
#pragma unroll
      for (int j = 0; j < 4; ++j) {
        int l = (((wr * 4 + j) * 16 + l16) << 7) + (lq << 4);
        af[j] = *(const bf16x8*)(Ab + swzb(l));
      }
#pragma unroll
      for (int nf = 0; nf < 2; ++nf) {
        int l = ((brow0 + nf * 16) << 7) + (lq << 4);
        bfr[nf] = *(const bf16x8*)(Bb + swzb(l));
      }
      if (kt + 1 < NT) stage_half(A, m0, (kt + 1) * 64, Anb, t);
      BAR();
      __builtin_amdgcn_s_setprio(1);
#pragma unroll
      for (int j = 0; j < 4; ++j)
#pragma unroll
        for (int nf = 0; nf < 2; ++nf)
          acc[j][nf] = MFMA_BF16(af[j], bfr[nf], acc[j][nf]);
      __builtin_amdgcn_s_setprio(0);
      BAR();
      // ---------- P2: kf=0, nf{2,3}; stage B(kt+2) ----------
#pragma unroll
      for (int nf = 0; nf < 2; ++nf) {
        int l = ((brow0 + (nf + 2) * 16) << 7) + (lq << 4);
        bfr[2 + nf] = *(const bf16x8*)(Bb + swzb(l));
      }
      if (kt + 2 < NT) {
        stage_half(Bt, (size_t)n0,       (kt + 2) * 64, BS1(bq2, 0), t);
        stage_half(Bt, (size_t)n0 + 128, (kt + 2) * 64, BS1(bq2, 1), t);
      }
      BAR();
      __builtin_amdgcn_s_setprio(1);
#pragma unroll
      for (int j = 0; j < 4; ++j)
#pragma unroll
        for (int nf = 0; nf < 2; ++nf)
          acc[j][2 + nf] = MFMA_BF16(af[j], bfr[2 + nf], acc[j][2 + nf]);
      __builtin_amdgcn_s_setprio(0);
      BAR();
      // ---------- P3: kf=1, nf{0,1} ----------
#pragma unroll
      for (int j = 0; j < 4; ++j) {
        int l = (((wr * 4 + j) * 16 + l16) << 7) + 64 + (lq << 4);
        af[j] = *(const bf16x8*)(Ab + swzb(l));
      }
#pragma unroll
      for (int nf = 0; nf < 2; ++nf) {
        int l = ((brow0 + nf * 16) << 7) + 64 + (lq << 4);
        bfr[nf] = *(const bf16x8*)(Bb + swzb(l));
      }
      BAR();
      __builtin_amdgcn_s_setprio(1);
#pragma unroll
      for (int j = 0; j < 4; ++j)
#pragma unroll
        for (int nf = 0; nf < 2; ++nf)
          acc[j][nf] = MFMA_BF16(af[j], bfr[nf], acc[j][nf]);
      __builtin_amdgcn_s_setprio(0);
      BAR();
      // ---------- P4: kf=1, nf{2,3}; counted vmcnt ----------
#pragma unroll
      for (int nf = 0; nf < 2; ++nf) {
        int l = ((brow0 + (nf + 2) * 16) << 7) + 64 + (lq << 4);
        bfr[2 + nf] = *(const bf16x8*)(Bb + swzb(l));
      }
      BAR();
      __builtin_amdgcn_s_setprio(1);
#pragma unroll
      for (int j = 0; j < 4; ++j)
#pragma unroll
        for (int nf = 0; nf < 2; ++nf)
          acc[j][2 + nf] = MFMA_BF16(af[j], bfr[2 + nf], acc[j][2 + nf]);
      __builtin_amdgcn_s_setprio(0);
      if (kt < NT - 2)       asm volatile("s_waitcnt vmcnt(4)" ::: "memory");
      else if (kt == NT - 2) asm volatile("s_waitcnt vmcnt(0)" ::: "memory");
      BAR();
      bql += 1; if (bql >= 3) bql -= 3;
    }
  }

  // ---- epilogue: C write ----
  constexpr int WRS = (MODE == 0) ? 128 : 64;   // wave M-stride
#pragma unroll
  for (int mf = 0; mf < MF; ++mf) {
    int rowb = (int)m0 + wr * WRS + mf * 16 + lq * 4;
#pragma unroll
    for (int nf = 0; nf < 4; ++nf) {
      int col = n0 + wc * 64 + nf * 16 + l16;
#pragma unroll
      for (int r = 0; r < 4; ++r) {
        float v = acc[mf][nf][r];
        int mrow = rowb + r;
        if (MODE == 0) {
          int grp = col >> 11, cw = col & 2047;
          int b = mrow >> 11, s = mrow & 2047, n = cw >> 7, h = cw & 127;
          ((bf16*)Cout)[(size_t)grp * 8388608 +
                        (((size_t)(b * 16 + n) * 2048 + s) << 7) + h] = (bf16)v;
        } else {
          ((float*)Cout)[((size_t)mrow << 11) + col] = v;
        }
      }
    }
  }
}

// ------------- Flash attention (causal): Q,K [B,N,S,H], Vt [B,N,H,S] -> AO [B,S,N,H] -------------
__global__ __launch_bounds__(512, 4) void k_attn(const bf16* __restrict__ Q,
                                                 const bf16* __restrict__ Kg,
                                                 const bf16* __restrict__ Vt,
                                                 bf16* __restrict__ AO) {
  __shared__ __align__(16) bf16 Ks[64 * 128];   // [s'][h], chunk-swizzled
  __shared__ __align__(16) bf16 Vs[128 * 64];   // [h][s'], chunk-swizzled
  __shared__ __align__(16) bf16 Ps[8][16][72];  // per-wave P, padded
  int bid = blockIdx.x;
  int half = bid >> 8;
  int bn = (half << 4) | ((bid >> 4) & 15);
  int qt = (bid & 15) ^ (half ? 15 : 0);
  int q0 = qt * 128;
  int t = threadIdx.x, wid = t >> 6, lane = t & 63;
  int l16 = lane & 15, lq = lane >> 4;
  size_t bnSH = (size_t)bn * kS * kH;

  int qrow_a = q0 + wid * 16 + l16;
  bf16x8 qf[4];
#pragma unroll
  for (int ks = 0; ks < 4; ++ks)
    qf[ks] = *(const bf16x8*)(Q + bnSH + (size_t)qrow_a * kH + ks * 32 + lq * 8);

  f32x4 oacc[8] = {};
  float mrun[4], lrun[4];
#pragma unroll
  for (int r = 0; r < 4; ++r) { mrun[r] = -1e30f; lrun[r] = 0.f; }

  int ntiles = (q0 + 128) >> 6;
  for (int kt = 0; kt < ntiles; ++kt) {
    int kv0 = kt * 64;
#pragma unroll
    for (int i = 0; i < 2; ++i) {
      int idx = i * 512 + t;
      {
        int row = idx >> 4, ch = idx & 15;
        int gch = ch ^ (row & 7);
        gload16(Kg + bnSH + (size_t)(kv0 + row) * kH + gch * 8,
                (char*)Ks + i * 8192 + wid * 1024);
      }
      {
        int row = idx >> 3, ch = idx & 7;
        int gch = ch ^ (row & 7);
        gload16(Vt + bnSH + (size_t)row * kS + kv0 + gch * 8,
                (char*)Vs + i * 8192 + wid * 1024);
      }
    }
    __syncthreads();

    f32x4 sacc[4] = {};
#pragma unroll
    for (int ks = 0; ks < 4; ++ks) {
#pragma unroll
      for (int ni = 0; ni < 4; ++ni) {
        int sp = ni * 16 + l16;
        int hb = (ks * 32 + lq * 8) * 2;
        bf16x8 kb = *(const bf16x8*)((const char*)Ks + sp * 256 + (hb ^ ((sp & 7) << 4)));
        sacc[ni] = MFMA_BF16(qf[ks], kb, sacc[ni]);
      }
    }

    bool need_mask = (kv0 + 63) > (q0 + wid * 16);
#pragma unroll
    for (int ni = 0; ni < 4; ++ni) {
      f32x4 v = sacc[ni] * kScale;
      if (need_mask) {
#pragma unroll
        for (int r = 0; r < 4; ++r) {
          int qrow = q0 + wid * 16 + lq * 4 + r;
          int col = kv0 + ni * 16 + l16;
          if (col > qrow) v[r] = -1e30f;
        }
      }
      sacc[ni] = v;
    }

#pragma unroll
    for (int r = 0; r < 4; ++r) {
      float pm = fmaxf(fmaxf(sacc[0][r], sacc[1][r]),
                       fmaxf(sacc[2][r], sacc[3][r]));
      pm = fmaxf(pm, __shfl_xor(pm, 1));
      pm = fmaxf(pm, __shfl_xor(pm, 2));
      pm = fmaxf(pm, __shfl_xor(pm, 4));
      pm = fmaxf(pm, __shfl_xor(pm, 8));
      float mold = mrun[r];
      float mnew = fmaxf(mold, pm);
      float alpha = exp2f((mold - mnew) * kLog2e);
      mrun[r] = mnew;
      float rs = 0.f;
#pragma unroll
      for (int ni = 0; ni < 4; ++ni) {
        float p = exp2f((sacc[ni][r] - mnew) * kLog2e);
        sacc[ni][r] = p;
        rs += p;
      }
      rs += __shfl_xor(rs, 1);
      rs += __shfl_xor(rs, 2);
      rs += __shfl_xor(rs, 4);
      rs += __shfl_xor(rs, 8);
      lrun[r] = lrun[r] * alpha + rs;
#pragma unroll
      for (int nj = 0; nj < 8; ++nj) oacc[nj][r] *= alpha;
    }

#pragma unroll
    for (int ni = 0; ni < 4; ++ni)
#pragma unroll
      for (int r = 0; r < 4; ++r)
        Ps[wid][lq * 4 + r][ni * 16 + l16] = (bf16)sacc[ni][r];

#pragma unroll
    for (int ks = 0; ks < 2; ++ks) {
      bf16x8 pa = *(const bf16x8*)&Ps[wid][l16][ks * 32 + lq * 8];
#pragma unroll
      for (int nj = 0; nj < 8; ++nj) {
        int h = nj * 16 + l16;
        int sb = (ks * 64 + lq * 16) ^ ((h & 7) << 4);
        bf16x8 vb = *(const bf16x8*)((const char*)Vs + h * 128 + sb);
        oacc[nj] = MFMA_BF16(pa, vb, oacc[nj]);
      }
    }
    __syncthreads();
  }

  int b = bn >> 4, n = bn & 15;
#pragma unroll
  for (int r = 0; r < 4; ++r) {
    float inv = 1.0f / lrun[r];
    int qrow = q0 + wid * 16 + lq * 4 + r;
#pragma unroll
    for (int nj = 0; nj < 8; ++nj) {
      float v = oacc[nj][r] * inv;
      AO[(((size_t)b * kS + qrow) * kN + n) * kH + nj * 16 + l16] = (bf16)v;
    }
  }
}

extern "C" void kernel_launch(void* const* d_in, const int* in_sizes, int n_in,
                              void* d_out, int out_size, void* d_ws, size_t ws_size,
                              hipStream_t stream) {
  (void)in_sizes; (void)n_in; (void)out_size; (void)ws_size;
  const float* x_q  = (const float*)d_in[0];
  const float* x_kv = (const float*)d_in[1];
  const float* WQ   = (const float*)d_in[2];
  const float* WK   = (const float*)d_in[3];
  const float* WV   = (const float*)d_in[4];
  const float* WO   = (const float*)d_in[5];
  float* out = (float*)d_out;
  char* w = (char*)d_ws;
  const size_t MB = 1ull << 20;
  bf16* xq  = (bf16*)(w + 0 * MB);    // 16MB; reused: trig tables after QKV-GEMM, then AO
  bf16* xkv = (bf16*)(w + 16 * MB);   // 16MB; reused as Vt
  bf16* WqT = (bf16*)(w + 32 * MB);   // 8MB  -- WqT/WkT/WvT contiguous = fused [6144][2048]
  bf16* WkT = (bf16*)(w + 40 * MB);
  bf16* WvT = (bf16*)(w + 48 * MB);
  bf16* WoT = (bf16*)(w + 56 * MB);
  bf16* Qb  = (bf16*)(w + 64 * MB);   // [B,N,S,H]; Kb=+16MB, Vb=+32MB (grp indexed)
  bf16* Kb  = (bf16*)(w + 80 * MB);
  bf16* Vb  = (bf16*)(w + 96 * MB);
  float* ctab = (float*)(w + 0 * MB); // lives in dead xq region (after QKV GEMM)
  float* stab = (float*)(w + 1 * MB);
  bf16* AO  = xq;                     // [B,S,N,H] — written by attn (tables dead by then)
  bf16* Vtb = xkv;                    // [B,N,H,S]

  k_cvt<<<8192, 256, 0, stream>>>(x_q, xq);
  k_cvt<<<8192, 256, 0, stream>>>(x_kv, xkv);
  k_tconv<<<1024, 256, 0, stream>>>(WQ, WqT);
  k_tconv<<<1024, 256, 0, stream>>>(WK, WkT);
  k_tconv<<<1024, 256, 0, stream>>>(WV, WvT);
  k_tconv<<<1024, 256, 0, stream>>>(WO, WoT);
  k_gemm8<0><<<384, 512, 0, stream>>>(xq, xkv, WqT, Qb);   // fused QKV
  k_trig<<<512, 256, 0, stream>>>(ctab, stab);             // xq dead -> tables
  k_rope<<<16384, 256, 0, stream>>>(Qb, Kb, ctab, stab);
  k_vtrans<<<2048, 256, 0, stream>>>(Vb, Vtb);
  k_attn<<<512, 512, 0, stream>>>(Qb, Kb, Vtb, AO);        // AO overwrites tables (dead)
  k_gemm8<1><<<256, 512, 0, stream>>>(AO, AO, WoT, out);   // output proj
}